// Round 17
// baseline (1167.104 us; speedup 1.0000x reference)
//
#include <hip/hip_runtime.h>
#include <math.h>

#define NB 96
#define NA 48
#define NF 128
#define NK 64
#define NL 6
#define NN (NB*NA)     // 4608 nodes
#define F3 (3*NF)      // 384
#define CUTF 5.0f
#define GAMMA_F ((float)(1.0 / (0.006103515625 + 1e-9)))
#define PI_F 3.14159265358979323846f

typedef __attribute__((ext_vector_type(8))) short short8;
typedef __attribute__((ext_vector_type(4))) float floatx4;

__device__ __forceinline__ float silu_f(float x) { return x / (1.0f + expf(-x)); }

__device__ __forceinline__ short f2bf(float x) {
    unsigned u = __builtin_bit_cast(unsigned, x);
    unsigned r = (u + 0x7fffu + ((u >> 16) & 1u)) >> 16;   // RNE
    return (short)r;
}
__device__ __forceinline__ float bf2f(short h) {
    unsigned u = ((unsigned)(unsigned short)h) << 16;
    return __builtin_bit_cast(float, u);
}
__device__ __forceinline__ floatx4 mfma1(short8 a, short8 b, floatx4 c) {
    return __builtin_amdgcn_mfma_f32_16x16x32_bf16(a, b, c, 0, 0, 0);
}
__device__ __forceinline__ floatx4 mfma3(short8 ah, short8 al, short8 bh, short8 bl, floatx4 c) {
    c = __builtin_amdgcn_mfma_f32_16x16x32_bf16(ah, bh, c, 0, 0, 0);
    c = __builtin_amdgcn_mfma_f32_16x16x32_bf16(al, bh, c, 0, 0, 0);
    c = __builtin_amdgcn_mfma_f32_16x16x32_bf16(ah, bl, c, 0, 0, 0);
    return c;
}

// ---------------- fused prep: weights -> bf16 hi/lo in MFMA B-FRAGMENT ORDER ----------------
__global__ void prep_kernel(const float* __restrict__ msg_w1, const float* __restrict__ msg_w2,
                            const float* __restrict__ rbf_w, const float* __restrict__ upd_U,
                            const float* __restrict__ upd_V, const float* __restrict__ upd_w1,
                            const float* __restrict__ upd_w2,
                            short* w1T_h, short* w1T_l, short* w2T_h, short* w2T_l,
                            short* rbfT_h, short* rbfT_l, short* UT_h, short* UT_l,
                            short* VT_h, short* VT_l, short* u1T_h, short* u1T_l,
                            short* u2T_h, short* u2T_l) {
    int m = blockIdx.y;
    int l = blockIdx.x / 384;
    int n = blockIdx.x % 384;
    const float* src; short* dh; short* dl; int K, N;
    switch (m) {
      case 0: src = msg_w1; dh = w1T_h; dl = w1T_l; K = NF;   N = NF; break;
      case 1: src = msg_w2; dh = w2T_h; dl = w2T_l; K = NF;   N = F3; break;
      case 2: src = rbf_w;  dh = rbfT_h;dl = rbfT_l;K = NK;   N = F3; break;
      case 3: src = upd_U;  dh = UT_h;  dl = UT_l;  K = NF;   N = NF; break;
      case 4: src = upd_V;  dh = VT_h;  dl = VT_l;  K = NF;   N = NF; break;
      case 5: src = upd_w1; dh = u1T_h; dl = u1T_l; K = 2*NF; N = NF; break;
      default:src = upd_w2; dh = u2T_h; dl = u2T_l; K = NF;   N = F3; break;
    }
    if (n >= N) return;
    for (int k = threadIdx.x; k < K; k += 64) {
        float x = src[((size_t)l*K + k)*N + n];
        short h = f2bf(x);
        size_t off = (size_t)l*N*K
                   + (size_t)((((n>>4)*(K>>5) + (k>>5))*4 + ((k>>3)&3))*128 + (n&15)*8 + (k&7));
        dh[off] = h;
        dl[off] = f2bf(x - bf2f(h));
    }
}

// ---------------- geometry (once): d, we, dir per (i,j) ----------------
__global__ void __launch_bounds__(256) geom_kernel(const float* __restrict__ pos,
                                                   float* __restrict__ dG,
                                                   float* __restrict__ weG,
                                                   float* __restrict__ dirG) {
    int e = blockIdx.x*256 + threadIdx.x;        // e < NN*NA
    int i = e / NA, j = e % NA;
    int b = i / NA, il = i % NA;
    int jg = b*NA + j;
    float dx = pos[i*3+0] - pos[jg*3+0];
    float dy = pos[i*3+1] - pos[jg*3+1];
    float dz = pos[i*3+2] - pos[jg*3+2];
    float d2 = dx*dx + dy*dy + dz*dz;
    float dd = sqrtf((j == il) ? 1.0f : d2);     // matches where(eye,1,d2)
    bool valid = (j != il) && (dd < CUTF);
    float we = valid ? 0.5f*(cosf(PI_F * dd / CUTF) + 1.0f) : 0.0f;
    dG[e] = dd;
    weG[e] = we;
    float inv = 1.0f / dd;
    dirG[0*(size_t)NN*NA + e] = dx*inv;
    dirG[1*(size_t)NN*NA + e] = dy*inv;
    dirG[2*(size_t)NN*NA + e] = dz*inv;
}

__global__ void zero_kernel(float* __restrict__ p) {
    p[(size_t)blockIdx.x * blockDim.x + threadIdx.x] = 0.f;
}

// ---------------- init + phi(0) ----------------
__global__ void __launch_bounds__(128) init_phi_kernel(
        const float* __restrict__ emb, const int* __restrict__ node_atom,
        const short* __restrict__ w1T_h, const short* __restrict__ w1T_l,
        const float* __restrict__ b1,
        const short* __restrict__ w2T_h, const short* __restrict__ w2T_l,
        const float* __restrict__ b2,
        float* __restrict__ s, float* __restrict__ v, float* __restrict__ phiT) {
    __shared__ short sH[16*NF], sL[16*NF];
    __shared__ short hH[16*NF], hL[16*NF];
    int t = threadIdx.x;
    int w = t >> 6, lane = t & 63, quad = lane >> 4, col = lane & 15;
    int n0 = blockIdx.x * 16;
    for (int e = t; e < 16*NF; e += 128) {
        int n = e >> 7, f = e & 127;
        int a = node_atom[n0+n];
        float x = emb[(size_t)a*NF + f];
        s[(size_t)(n0+n)*NF + f] = x;
        short h = f2bf(x);
        int ad = n*NF + (((f >> 3) ^ (n & 7)) << 3) + (f & 7);
        sH[ad] = h; sL[ad] = f2bf(x - bf2f(h));
    }
    for (int e = t; e < 16*F3; e += 128) v[(size_t)n0*F3 + e] = 0.f;
    __syncthreads();
    #pragma unroll
    for (int nt = 0; nt < 4; ++nt) {
        int fh = w*64 + nt*16 + col;
        floatx4 acc = (floatx4){0.f,0.f,0.f,0.f};
        #pragma unroll
        for (int ks = 0; ks < 4; ++ks) {
            int ad = col*NF + (((ks*4 + quad) ^ (col & 7)) << 3);
            size_t off = (size_t)((((w*4 + nt)*4 + ks)*4 + quad)*128) + col*8;
            acc = mfma3(*(short8*)&sH[ad], *(short8*)&sL[ad],
                        *(const short8*)(w1T_h + off), *(const short8*)(w1T_l + off), acc);
        }
        float bias = b1[fh];
        #pragma unroll
        for (int r = 0; r < 4; ++r) {
            int n = quad*4 + r;
            float hv = silu_f(acc[r] + bias);
            short h = f2bf(hv);
            int ad = n*NF + (((fh >> 3) ^ (n & 7)) << 3) + (fh & 7);
            hH[ad] = h; hL[ad] = f2bf(hv - bf2f(h));
        }
    }
    __syncthreads();
    #pragma unroll
    for (int nt = 0; nt < 12; ++nt) {
        int tt = w*192 + nt*16 + col;
        floatx4 acc = (floatx4){0.f,0.f,0.f,0.f};
        #pragma unroll
        for (int ks = 0; ks < 4; ++ks) {
            int ad = col*NF + (((ks*4 + quad) ^ (col & 7)) << 3);
            size_t off = (size_t)((((w*12 + nt)*4 + ks)*4 + quad)*128) + col*8;
            acc = mfma3(*(short8*)&hH[ad], *(short8*)&hL[ad],
                        *(const short8*)(w2T_h + off), *(const short8*)(w2T_l + off), acc);
        }
        float bias = b2[tt];
        floatx4 o;
        #pragma unroll
        for (int r = 0; r < 4; ++r) o[r] = acc[r] + bias;
        *(floatx4*)(phiT + (size_t)tt*NN + n0 + quad*4) = o;
    }
}

// ---------------- persistent per-graph kernel: all 6 layers, block = graph ----------------
// No cross-graph dataflow in PaiNN -> each block runs its graph's whole chain with only
// intra-block barriers. phiT/vT/s/v round-trip through the owning CU's L1.
// Message phase: R14's 8-atom-tile body, 6 tiles. Update phase: R14's 8-node body, 6 tiles.
// Buffers: message reads sA/vA writes sB/vB; update reads sB/vB writes sA/vA (+vT, phiT).
__global__ void __launch_bounds__(512, 1) graph_kernel(
        const float* __restrict__ dG, const float* __restrict__ weG,
        const float* __restrict__ dirG,
        const short* __restrict__ rbfT_h_all, const float* __restrict__ rbf_b_all,
        const short* __restrict__ UT_h_all, const short* __restrict__ VT_h_all,
        const short* __restrict__ u1T_h_all, const float* __restrict__ ub1_all,
        const short* __restrict__ u2T_h_all, const float* __restrict__ ub2_all,
        const short* __restrict__ w1T_h_all, const float* __restrict__ pb1_all,
        const short* __restrict__ w2T_h_all, const float* __restrict__ pb2_all,
        float* sA, float* vA, float* sB, float* vB,
        float* phiT, float* vT) {
    __shared__ short tkL[48*512];           // 48 KB
    __shared__ float weL[8][NA];
    __shared__ float dirL[3][8][NA];
    __shared__ short A1h[48*NF], A1l[48*NF];
    __shared__ short A2h[16*256];
    __shared__ short hH[16*NF];
    __shared__ float sF[8*132];
    int graph = blockIdx.x;
    int jbase = graph*NA;
    int t = threadIdx.x;
    int w = t >> 6, lane = t & 63, quad = lane >> 4, col = lane & 15;
    int f = w*16 + col;

    for (int l = 0; l < NL; ++l) {
        const short* rbfT_h = rbfT_h_all + (size_t)l*F3*NK;
        const float* rbf_b_l = rbf_b_all + (size_t)l*F3;
        __syncthreads();    // phiT/vT writes of previous layer visible
        float rb0 = rbf_b_l[f], rb1 = rbf_b_l[NF+f], rb2 = rbf_b_l[2*NF+f];
        short8 B[3][2];
        #pragma unroll
        for (int g = 0; g < 3; ++g)
            #pragma unroll
            for (int ks = 0; ks < 2; ++ks)
                B[g][ks] = *(const short8*)(rbfT_h + (size_t)((((g*8 + w)*2 + ks)*4 + quad)*128) + col*8);
        // j-side operands: graph-wide, hoisted ONCE per layer (atom-independent)
        floatx4 ph0[3], ph1[3], ph2[3], vj0[3], vj1[3], vj2[3];
        #pragma unroll
        for (int mt = 0; mt < 3; ++mt) {
            int jq = jbase + mt*16 + quad*4;
            ph0[mt] = *(const floatx4*)(phiT + (size_t)f*NN + jq);
            ph1[mt] = *(const floatx4*)(phiT + (size_t)(NF+f)*NN + jq);
            ph2[mt] = *(const floatx4*)(phiT + (size_t)(2*NF+f)*NN + jq);
            vj0[mt] = *(const floatx4*)(vT + (size_t)(0*NF+f)*NN + jq);
            vj1[mt] = *(const floatx4*)(vT + (size_t)(1*NF+f)*NN + jq);
            vj2[mt] = *(const floatx4*)(vT + (size_t)(2*NF+f)*NN + jq);
        }
        // ---- message phase: 6 tiles of 8 atoms ----
        for (int tile = 0; tile < 6; ++tile) {
            int n0 = jbase + tile*8;
            __syncthreads();           // protect tkL/weL/dirL reuse across tiles
            for (int u = t; u < 768; u += 512) {
                int p = u >> 1, half = u & 1;
                int ii = p / NA, j = p % NA;
                int i = n0 + ii;
                float dd = dG[(size_t)i*NA + j];
                float we = weG[(size_t)i*NA + j];
                if (half == 0) {
                    weL[ii][j] = we;
                    dirL[0][ii][j] = dirG[0*(size_t)NN*NA + (size_t)i*NA + j];
                    dirL[1][ii][j] = dirG[1*(size_t)NN*NA + (size_t)i*NA + j];
                    dirL[2][ii][j] = dirG[2*(size_t)NN*NA + (size_t)i*NA + j];
                }
                int mt = j >> 4, colj = j & 15;
                int base = ((ii*3 + mt)*2 + half) << 9;
                #pragma unroll
                for (int c = 0; c < 4; ++c) {
                    short8 h8;
                    #pragma unroll
                    for (int kk = 0; kk < 8; ++kk) {
                        int k = half*32 + c*8 + kk;
                        float cen = CUTF * (float)k / 63.0f;
                        float df = dd - cen;
                        h8[kk] = f2bf(__expf(-GAMMA_F * df * df) * we);
                    }
                    *(short8*)&tkL[base + (c*16 + colj)*8] = h8;
                }
            }
            __syncthreads();
            for (int ia = 0; ia < 8; ++ia) {
                floatx4 C[3][3];
                #pragma unroll
                for (int g = 0; g < 3; ++g)
                    #pragma unroll
                    for (int mt = 0; mt < 3; ++mt) C[g][mt] = (floatx4){0.f,0.f,0.f,0.f};
                #pragma unroll
                for (int mt = 0; mt < 3; ++mt) {
                    #pragma unroll
                    for (int ks = 0; ks < 2; ++ks) {
                        short8 a = *(short8*)&tkL[(((ia*3 + mt)*2 + ks) << 9) + lane*8];
                        #pragma unroll
                        for (int g = 0; g < 3; ++g)
                            C[g][mt] = mfma1(a, B[g][ks], C[g][mt]);
                    }
                }
                int i = n0 + ia;
                float accS = 0.f, av0 = 0.f, av1 = 0.f, av2 = 0.f;
                #pragma unroll
                for (int mt = 0; mt < 3; ++mt) {
                    int jq = mt*16 + quad*4;
                    floatx4 we4 = *(const floatx4*)&weL[ia][jq];
                    floatx4 d0 = *(const floatx4*)&dirL[0][ia][jq];
                    floatx4 d1 = *(const floatx4*)&dirL[1][ia][jq];
                    floatx4 d2 = *(const floatx4*)&dirL[2][ia][jq];
                    #pragma unroll
                    for (int r = 0; r < 4; ++r) {
                        float Wf0 = fmaf(rb0, we4[r], C[0][mt][r]);
                        accS = fmaf(ph0[mt][r], Wf0, accS);
                        float Wf1 = fmaf(rb1, we4[r], C[1][mt][r]);
                        float x1 = ph1[mt][r] * Wf1;
                        av0 = fmaf(x1, vj0[mt][r], av0);
                        av1 = fmaf(x1, vj1[mt][r], av1);
                        av2 = fmaf(x1, vj2[mt][r], av2);
                        float Wf2 = fmaf(rb2, we4[r], C[2][mt][r]);
                        float x2 = ph2[mt][r] * Wf2;
                        av0 = fmaf(x2, d0[r], av0);
                        av1 = fmaf(x2, d1[r], av1);
                        av2 = fmaf(x2, d2[r], av2);
                    }
                }
                accS += __shfl_xor(accS, 16, 64); accS += __shfl_xor(accS, 32, 64);
                av0 += __shfl_xor(av0, 16, 64);   av0 += __shfl_xor(av0, 32, 64);
                av1 += __shfl_xor(av1, 16, 64);   av1 += __shfl_xor(av1, 32, 64);
                av2 += __shfl_xor(av2, 16, 64);   av2 += __shfl_xor(av2, 32, 64);
                if (quad == 0) {
                    sB[(size_t)i*NF + f]        = sA[(size_t)i*NF + f]        + accS;
                    vB[(size_t)i*F3 + f]        = vA[(size_t)i*F3 + f]        + av0;
                    vB[(size_t)i*F3 + NF + f]   = vA[(size_t)i*F3 + NF + f]   + av1;
                    vB[(size_t)i*F3 + 2*NF + f] = vA[(size_t)i*F3 + 2*NF + f] + av2;
                }
            }
        }
        // ---- update (+ phi for next layer) phase: 6 tiles of 8 nodes ----
        int doPhi = (l + 1 < NL);
        int lp = doPhi ? (l + 1) : 0;
        const short* UT_h  = UT_h_all  + (size_t)l*NF*NF;
        const short* VT_h  = VT_h_all  + (size_t)l*NF*NF;
        const short* u1T_h = u1T_h_all + (size_t)l*NF*2*NF;
        const float* b1u   = ub1_all   + (size_t)l*NF;
        const short* u2T_h = u2T_h_all + (size_t)l*F3*NF;
        const float* b2u   = ub2_all   + (size_t)l*F3;
        const short* pw1_h = w1T_h_all + (size_t)lp*NF*NF;
        const float* pb1   = pb1_all   + (size_t)lp*NF;
        const short* pw2_h = w2T_h_all + (size_t)lp*F3*NF;
        const float* pb2   = pb2_all   + (size_t)lp*F3;
        for (int tile = 0; tile < 6; ++tile) {
            int n0 = jbase + tile*8;
            __syncthreads();           // message done / protect staging reuse
            for (int e = t; e < 8*F3; e += 512) {
                int n = e / F3, cf = e % F3;
                int c = cf >> 7, ff = cf & 127;
                float x = vB[(size_t)(n0+n)*F3 + cf];
                int row = c*16 + n;
                short h = f2bf(x);
                int ad = row*NF + (((ff >> 3) ^ (row & 7)) << 3) + (ff & 7);
                A1h[ad] = h; A1l[ad] = f2bf(x - bf2f(h));
            }
            for (int e = t; e < 8*NF; e += 512) {
                int n = e >> 7, ff = e & 127;
                float x = sB[(size_t)(n0+n)*NF + ff];
                sF[n*132 + ff] = x;
                int ad = n*256 + (((ff >> 3) ^ (n & 7)) << 3) + (ff & 7);
                A2h[ad] = f2bf(x);
            }
            __syncthreads();
            floatx4 Uacc[3], Vacc[3];
            #pragma unroll
            for (int mt = 0; mt < 3; ++mt) { Uacc[mt] = (floatx4){0.f,0.f,0.f,0.f}; Vacc[mt] = (floatx4){0.f,0.f,0.f,0.f}; }
            #pragma unroll
            for (int ks = 0; ks < 4; ++ks) {
                size_t off = (size_t)(((w*4 + ks)*4 + quad)*128) + col*8;
                short8 BU = *(const short8*)(UT_h + off);
                short8 BV = *(const short8*)(VT_h + off);
                #pragma unroll
                for (int mt = 0; mt < 3; ++mt) {
                    int row = mt*16 + col;
                    int ad = row*NF + (((ks*4 + quad) ^ (row & 7)) << 3);
                    short8 ah = *(short8*)&A1h[ad];
                    Uacc[mt] = mfma1(ah, BU, Uacc[mt]);
                    Vacc[mt] = mfma1(ah, BV, Vacc[mt]);
                }
            }
            if (quad < 2) {
                #pragma unroll
                for (int r = 0; r < 4; ++r) {
                    int n = quad*4 + r;          // n < 8
                    float v0 = Vacc[0][r], v1 = Vacc[1][r], v2 = Vacc[2][r];
                    float vn = sqrtf(v0*v0 + v1*v1 + v2*v2 + 1e-8f);
                    int ad = n*256 + ((((128 + f) >> 3) ^ (n & 7)) << 3) + (f & 7);
                    A2h[ad] = f2bf(vn);
                }
            }
            __syncthreads();
            {
                floatx4 H = (floatx4){0.f,0.f,0.f,0.f};
                #pragma unroll
                for (int ks = 0; ks < 8; ++ks) {
                    int ad = col*256 + (((ks*4 + quad) ^ (col & 7)) << 3);
                    short8 ah = *(short8*)&A2h[ad];
                    size_t off = (size_t)(((w*8 + ks)*4 + quad)*128) + col*8;
                    H = mfma1(ah, *(const short8*)(u1T_h + off), H);
                }
                float bias = b1u[f];
                if (quad < 2) {
                    #pragma unroll
                    for (int r = 0; r < 4; ++r) {
                        int n = quad*4 + r;
                        float hv = silu_f(H[r] + bias);
                        int ad = n*NF + (((f >> 3) ^ (n & 7)) << 3) + (f & 7);
                        hH[ad] = f2bf(hv);
                    }
                }
            }
            __syncthreads();
            floatx4 O[3];
            #pragma unroll
            for (int gg = 0; gg < 3; ++gg) O[gg] = (floatx4){0.f,0.f,0.f,0.f};
            #pragma unroll
            for (int ks = 0; ks < 4; ++ks) {
                int ad = col*NF + (((ks*4 + quad) ^ (col & 7)) << 3);
                short8 ah = *(short8*)&hH[ad];
                #pragma unroll
                for (int gg = 0; gg < 3; ++gg) {
                    size_t off = (size_t)((((gg*8 + w)*4 + ks)*4 + quad)*128) + col*8;
                    O[gg] = mfma1(ah, *(const short8*)(u2T_h + off), O[gg]);
                }
            }
            __syncthreads();        // A2h free -> reuse for s_new (phi A operand)
            short* pH = A2h;
            if (quad < 2) {
                float bavv = b2u[f], basv = b2u[NF + f], bass = b2u[2*NF + f];
                #pragma unroll
                for (int r = 0; r < 4; ++r) {
                    int n = quad*4 + r;          // n < 8
                    float avv = O[0][r] + bavv;
                    float asv = O[1][r] + basv;
                    float ass = O[2][r] + bass;
                    float dot = Uacc[0][r]*Vacc[0][r] + Uacc[1][r]*Vacc[1][r] + Uacc[2][r]*Vacc[2][r];
                    float snew = sF[n*132 + f] + asv*dot + ass;
                    sA[(size_t)(n0+n)*NF + f] = snew;
                    int adS = n*NF + (((f >> 3) ^ (n & 7)) << 3) + (f & 7);
                    pH[adS] = f2bf(snew);
                    #pragma unroll
                    for (int c = 0; c < 3; ++c) {
                        int row = c*16 + n;
                        int ad = row*NF + (((f >> 3) ^ (row & 7)) << 3) + (f & 7);
                        float vold = bf2f(A1h[ad]) + bf2f(A1l[ad]);   // exact fp32 v_old
                        float vnew = vold + avv*Uacc[c][r];
                        vA[(size_t)(n0+n)*F3 + c*NF + f] = vnew;
                        vT[(size_t)(c*NF + f)*NN + n0 + n] = vnew;
                    }
                }
            }
            if (doPhi) {
                __syncthreads();
                // phi GEMM1: wave w -> feature tile w
                {
                    floatx4 acc = (floatx4){0.f,0.f,0.f,0.f};
                    #pragma unroll
                    for (int ks = 0; ks < 4; ++ks) {
                        int ad = col*NF + (((ks*4 + quad) ^ (col & 7)) << 3);
                        size_t off = (size_t)(((w*4 + ks)*4 + quad)*128) + col*8;
                        acc = mfma1(*(short8*)&pH[ad], *(const short8*)(pw1_h + off), acc);
                    }
                    float bias = pb1[f];
                    if (quad < 2) {
                        #pragma unroll
                        for (int r = 0; r < 4; ++r) {
                            int n = quad*4 + r;
                            float hv = silu_f(acc[r] + bias);
                            int ad = n*NF + (((f >> 3) ^ (n & 7)) << 3) + (f & 7);
                            hH[ad] = f2bf(hv);
                        }
                    }
                }
                __syncthreads();
                // phi GEMM2: 8 waves x 3 tiles
                #pragma unroll
                for (int nt = 0; nt < 3; ++nt) {
                    int tt = (w*3 + nt)*16 + col;
                    floatx4 acc = (floatx4){0.f,0.f,0.f,0.f};
                    #pragma unroll
                    for (int ks = 0; ks < 4; ++ks) {
                        int ad = col*NF + (((ks*4 + quad) ^ (col & 7)) << 3);
                        size_t off = (size_t)((((w*3 + nt)*4 + ks)*4 + quad)*128) + col*8;
                        acc = mfma1(*(short8*)&hH[ad], *(const short8*)(pw2_h + off), acc);
                    }
                    float bias = pb2[tt];
                    if (quad < 2) {
                        floatx4 o;
                        #pragma unroll
                        for (int r = 0; r < 4; ++r) o[r] = acc[r] + bias;
                        *(floatx4*)(phiT + (size_t)tt*NN + n0 + quad*4) = o;
                    }
                }
            }
        }
    }
}

// ---------------- output head ----------------
__global__ void zero_out_kernel(float* __restrict__ out) {
    out[threadIdx.x] = 0.f;
}

__global__ void out_kernel(const float* __restrict__ s,
                           const float* __restrict__ w1, const float* __restrict__ b1,
                           const float* __restrict__ w2, const float* __restrict__ b2,
                           float* __restrict__ out) {
    int n = blockIdx.x;
    int f = threadIdx.x;
    __shared__ float sh[NF];
    __shared__ float r2[2];
    sh[f] = s[n*NF + f];
    __syncthreads();
    float acc = b1[f];
    for (int g = 0; g < NF; ++g) acc = fmaf(sh[g], w1[g*NF + f], acc);
    float p = silu_f(acc) * w2[f];
    #pragma unroll
    for (int off = 32; off > 0; off >>= 1) p += __shfl_down(p, off, 64);
    if ((f & 63) == 0) r2[f >> 6] = p;
    __syncthreads();
    if (f == 0) atomicAdd(&out[n / NA], r2[0] + r2[1] + b2[0]);
}

extern "C" void kernel_launch(void* const* d_in, const int* in_sizes, int n_in,
                              void* d_out, int out_size, void* d_ws, size_t ws_size,
                              hipStream_t stream) {
    (void)in_sizes; (void)n_in; (void)out_size; (void)ws_size;
    const float* pos      = (const float*)d_in[1];
    const int*   node_atom= (const int*)  d_in[3];
    const float* emb      = (const float*)d_in[4];
    const float* msg_w1   = (const float*)d_in[5];
    const float* msg_b1   = (const float*)d_in[6];
    const float* msg_w2   = (const float*)d_in[7];
    const float* msg_b2   = (const float*)d_in[8];
    const float* rbf_w    = (const float*)d_in[9];
    const float* rbf_b    = (const float*)d_in[10];
    const float* upd_U    = (const float*)d_in[11];
    const float* upd_V    = (const float*)d_in[12];
    const float* upd_w1   = (const float*)d_in[13];
    const float* upd_b1   = (const float*)d_in[14];
    const float* upd_w2   = (const float*)d_in[15];
    const float* upd_b2   = (const float*)d_in[16];
    const float* out_w1   = (const float*)d_in[17];
    const float* out_b1   = (const float*)d_in[18];
    const float* out_w2   = (const float*)d_in[19];
    const float* out_b2   = (const float*)d_in[20];
    float* out = (float*)d_out;

    float* ws   = (float*)d_ws;
    float* sA   = ws; ws += (size_t)NN*NF;
    float* sB   = ws; ws += (size_t)NN*NF;
    float* vA   = ws; ws += (size_t)NN*F3;
    float* vB   = ws; ws += (size_t)NN*F3;
    float* phiT = ws; ws += (size_t)F3*NN;
    float* vT   = ws; ws += (size_t)F3*NN;
    float* dG   = ws; ws += (size_t)NN*NA;
    float* weG  = ws; ws += (size_t)NN*NA;
    float* dirG = ws; ws += (size_t)3*NN*NA;
    short* sp    = (short*)ws;
    short* w1T_h = sp; sp += (size_t)NL*NF*NF;
    short* w1T_l = sp; sp += (size_t)NL*NF*NF;
    short* w2T_h = sp; sp += (size_t)NL*F3*NF;
    short* w2T_l = sp; sp += (size_t)NL*F3*NF;
    short* rbfT_h= sp; sp += (size_t)NL*F3*NK;
    short* rbfT_l= sp; sp += (size_t)NL*F3*NK;
    short* UT_h  = sp; sp += (size_t)NL*NF*NF;
    short* UT_l  = sp; sp += (size_t)NL*NF*NF;
    short* VT_h  = sp; sp += (size_t)NL*NF*NF;
    short* VT_l  = sp; sp += (size_t)NL*NF*NF;
    short* u1T_h = sp; sp += (size_t)NL*NF*2*NF;
    short* u1T_l = sp; sp += (size_t)NL*NF*2*NF;
    short* u2T_h = sp; sp += (size_t)NL*F3*NF;
    short* u2T_l = sp; sp += (size_t)NL*F3*NF;

    prep_kernel<<<dim3(NL*384, 7), 64, 0, stream>>>(msg_w1, msg_w2, rbf_w, upd_U, upd_V, upd_w1, upd_w2,
                                                    w1T_h, w1T_l, w2T_h, w2T_l, rbfT_h, rbfT_l,
                                                    UT_h, UT_l, VT_h, VT_l, u1T_h, u1T_l, u2T_h, u2T_l);
    geom_kernel<<<(NN*NA)/256, 256, 0, stream>>>(pos, dG, weG, dirG);
    zero_kernel<<<(F3*NN)/256, 256, 0, stream>>>(vT);
    init_phi_kernel<<<NN/16, 128, 0, stream>>>(emb, node_atom,
                                               w1T_h, w1T_l, msg_b1, w2T_h, w2T_l, msg_b2,
                                               sA, vA, phiT);

    graph_kernel<<<NB, 512, 0, stream>>>(dG, weG, dirG,
                                         rbfT_h, rbf_b,
                                         UT_h, VT_h, u1T_h, upd_b1, u2T_h, upd_b2,
                                         w1T_h, msg_b1, w2T_h, msg_b2,
                                         sA, vA, sB, vB, phiT, vT);

    zero_out_kernel<<<1, NB, 0, stream>>>(out);
    out_kernel<<<NN, NF, 0, stream>>>(sA, out_w1, out_b1, out_w2, out_b2, out);
}

// Round 18
// 592.587 us; speedup vs baseline: 1.9695x; 1.9695x over previous
//
#include <hip/hip_runtime.h>
#include <math.h>

#define NB 96
#define NA 48
#define NF 128
#define NK 64
#define NL 6
#define NN (NB*NA)     // 4608 nodes
#define F3 (3*NF)      // 384
#define CUTF 5.0f
#define GAMMA_F ((float)(1.0 / (0.006103515625 + 1e-9)))
#define PI_F 3.14159265358979323846f

typedef __attribute__((ext_vector_type(8))) short short8;
typedef __attribute__((ext_vector_type(4))) float floatx4;
typedef __attribute__((ext_vector_type(2))) float floatx2;

#define LO2(v) __builtin_shufflevector(v, v, 0, 1)
#define HI2(v) __builtin_shufflevector(v, v, 2, 3)

__device__ __forceinline__ float silu_f(float x) { return x / (1.0f + expf(-x)); }

__device__ __forceinline__ short f2bf(float x) {
    unsigned u = __builtin_bit_cast(unsigned, x);
    unsigned r = (u + 0x7fffu + ((u >> 16) & 1u)) >> 16;   // RNE
    return (short)r;
}
__device__ __forceinline__ float bf2f(short h) {
    unsigned u = ((unsigned)(unsigned short)h) << 16;
    return __builtin_bit_cast(float, u);
}
__device__ __forceinline__ floatx4 mfma1(short8 a, short8 b, floatx4 c) {
    return __builtin_amdgcn_mfma_f32_16x16x32_bf16(a, b, c, 0, 0, 0);
}
__device__ __forceinline__ floatx4 mfma3(short8 ah, short8 al, short8 bh, short8 bl, floatx4 c) {
    c = __builtin_amdgcn_mfma_f32_16x16x32_bf16(ah, bh, c, 0, 0, 0);
    c = __builtin_amdgcn_mfma_f32_16x16x32_bf16(al, bh, c, 0, 0, 0);
    c = __builtin_amdgcn_mfma_f32_16x16x32_bf16(ah, bl, c, 0, 0, 0);
    return c;
}

// ---------------- fused prep: weights -> bf16 hi/lo in MFMA B-FRAGMENT ORDER ----------------
__global__ void prep_kernel(const float* __restrict__ msg_w1, const float* __restrict__ msg_w2,
                            const float* __restrict__ rbf_w, const float* __restrict__ upd_U,
                            const float* __restrict__ upd_V, const float* __restrict__ upd_w1,
                            const float* __restrict__ upd_w2,
                            short* w1T_h, short* w1T_l, short* w2T_h, short* w2T_l,
                            short* rbfT_h, short* rbfT_l, short* UT_h, short* UT_l,
                            short* VT_h, short* VT_l, short* u1T_h, short* u1T_l,
                            short* u2T_h, short* u2T_l) {
    int m = blockIdx.y;
    int l = blockIdx.x / 384;
    int n = blockIdx.x % 384;
    const float* src; short* dh; short* dl; int K, N;
    switch (m) {
      case 0: src = msg_w1; dh = w1T_h; dl = w1T_l; K = NF;   N = NF; break;
      case 1: src = msg_w2; dh = w2T_h; dl = w2T_l; K = NF;   N = F3; break;
      case 2: src = rbf_w;  dh = rbfT_h;dl = rbfT_l;K = NK;   N = F3; break;
      case 3: src = upd_U;  dh = UT_h;  dl = UT_l;  K = NF;   N = NF; break;
      case 4: src = upd_V;  dh = VT_h;  dl = VT_l;  K = NF;   N = NF; break;
      case 5: src = upd_w1; dh = u1T_h; dl = u1T_l; K = 2*NF; N = NF; break;
      default:src = upd_w2; dh = u2T_h; dl = u2T_l; K = NF;   N = F3; break;
    }
    if (n >= N) return;
    for (int k = threadIdx.x; k < K; k += 64) {
        float x = src[((size_t)l*K + k)*N + n];
        short h = f2bf(x);
        size_t off = (size_t)l*N*K
                   + (size_t)((((n>>4)*(K>>5) + (k>>5))*4 + ((k>>3)&3))*128 + (n&15)*8 + (k&7));
        dh[off] = h;
        dl[off] = f2bf(x - bf2f(h));
    }
}

// ---------------- geometry (once): d, we, dir per (i,j) ----------------
__global__ void __launch_bounds__(256) geom_kernel(const float* __restrict__ pos,
                                                   float* __restrict__ dG,
                                                   float* __restrict__ weG,
                                                   float* __restrict__ dirG) {
    int e = blockIdx.x*256 + threadIdx.x;        // e < NN*NA
    int i = e / NA, j = e % NA;
    int b = i / NA, il = i % NA;
    int jg = b*NA + j;
    float dx = pos[i*3+0] - pos[jg*3+0];
    float dy = pos[i*3+1] - pos[jg*3+1];
    float dz = pos[i*3+2] - pos[jg*3+2];
    float d2 = dx*dx + dy*dy + dz*dz;
    float dd = sqrtf((j == il) ? 1.0f : d2);     // matches where(eye,1,d2)
    bool valid = (j != il) && (dd < CUTF);
    float we = valid ? 0.5f*(cosf(PI_F * dd / CUTF) + 1.0f) : 0.0f;
    dG[e] = dd;
    weG[e] = we;
    float inv = 1.0f / dd;
    dirG[0*(size_t)NN*NA + e] = dx*inv;
    dirG[1*(size_t)NN*NA + e] = dy*inv;
    dirG[2*(size_t)NN*NA + e] = dz*inv;
}

__global__ void zero_kernel(float* __restrict__ p) {
    p[(size_t)blockIdx.x * blockDim.x + threadIdx.x] = 0.f;
}

// ---------------- init + phi(0) ----------------
__global__ void __launch_bounds__(128) init_phi_kernel(
        const float* __restrict__ emb, const int* __restrict__ node_atom,
        const short* __restrict__ w1T_h, const short* __restrict__ w1T_l,
        const float* __restrict__ b1,
        const short* __restrict__ w2T_h, const short* __restrict__ w2T_l,
        const float* __restrict__ b2,
        float* __restrict__ s, float* __restrict__ v, float* __restrict__ phiT) {
    __shared__ short sH[16*NF], sL[16*NF];
    __shared__ short hH[16*NF], hL[16*NF];
    int t = threadIdx.x;
    int w = t >> 6, lane = t & 63, quad = lane >> 4, col = lane & 15;
    int n0 = blockIdx.x * 16;
    for (int e = t; e < 16*NF; e += 128) {
        int n = e >> 7, f = e & 127;
        int a = node_atom[n0+n];
        float x = emb[(size_t)a*NF + f];
        s[(size_t)(n0+n)*NF + f] = x;
        short h = f2bf(x);
        int ad = n*NF + (((f >> 3) ^ (n & 7)) << 3) + (f & 7);
        sH[ad] = h; sL[ad] = f2bf(x - bf2f(h));
    }
    for (int e = t; e < 16*F3; e += 128) v[(size_t)n0*F3 + e] = 0.f;
    __syncthreads();
    #pragma unroll
    for (int nt = 0; nt < 4; ++nt) {
        int fh = w*64 + nt*16 + col;
        floatx4 acc = (floatx4){0.f,0.f,0.f,0.f};
        #pragma unroll
        for (int ks = 0; ks < 4; ++ks) {
            int ad = col*NF + (((ks*4 + quad) ^ (col & 7)) << 3);
            size_t off = (size_t)((((w*4 + nt)*4 + ks)*4 + quad)*128) + col*8;
            acc = mfma3(*(short8*)&sH[ad], *(short8*)&sL[ad],
                        *(const short8*)(w1T_h + off), *(const short8*)(w1T_l + off), acc);
        }
        float bias = b1[fh];
        #pragma unroll
        for (int r = 0; r < 4; ++r) {
            int n = quad*4 + r;
            float hv = silu_f(acc[r] + bias);
            short h = f2bf(hv);
            int ad = n*NF + (((fh >> 3) ^ (n & 7)) << 3) + (fh & 7);
            hH[ad] = h; hL[ad] = f2bf(hv - bf2f(h));
        }
    }
    __syncthreads();
    #pragma unroll
    for (int nt = 0; nt < 12; ++nt) {
        int tt = w*192 + nt*16 + col;
        floatx4 acc = (floatx4){0.f,0.f,0.f,0.f};
        #pragma unroll
        for (int ks = 0; ks < 4; ++ks) {
            int ad = col*NF + (((ks*4 + quad) ^ (col & 7)) << 3);
            size_t off = (size_t)((((w*12 + nt)*4 + ks)*4 + quad)*128) + col*8;
            acc = mfma3(*(short8*)&hH[ad], *(short8*)&hL[ad],
                        *(const short8*)(w2T_h + off), *(const short8*)(w2T_l + off), acc);
        }
        float bias = b2[tt];
        floatx4 o;
        #pragma unroll
        for (int r = 0; r < 4; ++r) o[r] = acc[r] + bias;
        *(floatx4*)(phiT + (size_t)tt*NN + n0 + quad*4) = o;
    }
}

// ---------------- message: block = (graph, 8-atom tile), 512 thr ----------------
// Combine loop uses packed float2 math (v_pk_fma_f32) — halves combine VALU issue.
__global__ void __launch_bounds__(512) message_kernel(
        const float* __restrict__ sIn, const float* __restrict__ vIn,
        const float* __restrict__ phiT, const float* __restrict__ vT,
        const float* __restrict__ dG, const float* __restrict__ weG,
        const float* __restrict__ dirG,
        const short* __restrict__ rbfT_h,
        const float* __restrict__ rbf_b_l,
        float* __restrict__ sOut, float* __restrict__ vOut) {
    __shared__ short tkL[48*512];           // 48 KB
    __shared__ float weL[8][NA];
    __shared__ float dirL[3][8][NA];
    int raw = blockIdx.x;                   // 576 = 8 xcd x 12 graphs x 6 tiles
    int xcd = raw & 7, idx = raw >> 3;
    int graph = xcd + 8*(idx % 12);
    int itile = idx / 12;
    int i0l = itile*8, jbase = graph*NA;
    int n0 = jbase + i0l;
    int t = threadIdx.x;
    int w = t >> 6, lane = t & 63, quad = lane >> 4, col = lane & 15;
    int f = w*16 + col;
    float rb0 = rbf_b_l[f], rb1 = rbf_b_l[NF+f], rb2 = rbf_b_l[2*NF+f];
    floatx2 rb0v = {rb0, rb0}, rb1v = {rb1, rb1}, rb2v = {rb2, rb2};
    short8 B[3][2];
    #pragma unroll
    for (int g = 0; g < 3; ++g)
        #pragma unroll
        for (int ks = 0; ks < 2; ++ks)
            B[g][ks] = *(const short8*)(rbfT_h + (size_t)((((g*8 + w)*2 + ks)*4 + quad)*128) + col*8);
    floatx4 ph0[3], ph1[3], ph2[3], vj0[3], vj1[3], vj2[3];
    #pragma unroll
    for (int mt = 0; mt < 3; ++mt) {
        int jq = jbase + mt*16 + quad*4;
        ph0[mt] = *(const floatx4*)(phiT + (size_t)f*NN + jq);
        ph1[mt] = *(const floatx4*)(phiT + (size_t)(NF+f)*NN + jq);
        ph2[mt] = *(const floatx4*)(phiT + (size_t)(2*NF+f)*NN + jq);
        vj0[mt] = *(const floatx4*)(vT + (size_t)(0*NF+f)*NN + jq);
        vj1[mt] = *(const floatx4*)(vT + (size_t)(1*NF+f)*NN + jq);
        vj2[mt] = *(const floatx4*)(vT + (size_t)(2*NF+f)*NN + jq);
    }
    for (int u = t; u < 768; u += 512) {
        int p = u >> 1, half = u & 1;
        int ii = p / NA, j = p % NA;
        int i = n0 + ii;
        float dd = dG[(size_t)i*NA + j];
        float we = weG[(size_t)i*NA + j];
        if (half == 0) {
            weL[ii][j] = we;
            dirL[0][ii][j] = dirG[0*(size_t)NN*NA + (size_t)i*NA + j];
            dirL[1][ii][j] = dirG[1*(size_t)NN*NA + (size_t)i*NA + j];
            dirL[2][ii][j] = dirG[2*(size_t)NN*NA + (size_t)i*NA + j];
        }
        int mt = j >> 4, colj = j & 15;
        int base = ((ii*3 + mt)*2 + half) << 9;
        #pragma unroll
        for (int c = 0; c < 4; ++c) {
            short8 h8;
            #pragma unroll
            for (int kk = 0; kk < 8; ++kk) {
                int k = half*32 + c*8 + kk;
                float cen = CUTF * (float)k / 63.0f;
                float df = dd - cen;
                h8[kk] = f2bf(__expf(-GAMMA_F * df * df) * we);
            }
            *(short8*)&tkL[base + (c*16 + colj)*8] = h8;
        }
    }
    __syncthreads();
    for (int ia = 0; ia < 8; ++ia) {
        floatx4 C[3][3];
        #pragma unroll
        for (int g = 0; g < 3; ++g)
            #pragma unroll
            for (int mt = 0; mt < 3; ++mt) C[g][mt] = (floatx4){0.f,0.f,0.f,0.f};
        #pragma unroll
        for (int mt = 0; mt < 3; ++mt) {
            #pragma unroll
            for (int ks = 0; ks < 2; ++ks) {
                short8 a = *(short8*)&tkL[(((ia*3 + mt)*2 + ks) << 9) + lane*8];
                #pragma unroll
                for (int g = 0; g < 3; ++g)
                    C[g][mt] = mfma1(a, B[g][ks], C[g][mt]);
            }
        }
        int i = n0 + ia;
        floatx2 accS2 = {0.f,0.f}, av02 = {0.f,0.f}, av12 = {0.f,0.f}, av22 = {0.f,0.f};
        #pragma unroll
        for (int mt = 0; mt < 3; ++mt) {
            int jq = mt*16 + quad*4;
            floatx4 we4 = *(const floatx4*)&weL[ia][jq];
            floatx4 d0 = *(const floatx4*)&dirL[0][ia][jq];
            floatx4 d1 = *(const floatx4*)&dirL[1][ia][jq];
            floatx4 d2 = *(const floatx4*)&dirL[2][ia][jq];
            // packed pair 0 (r = 0,1)
            {
                floatx2 we2 = LO2(we4);
                floatx2 Wf0 = rb0v*we2 + LO2(C[0][mt]);
                accS2 += LO2(ph0[mt]) * Wf0;
                floatx2 Wf1 = rb1v*we2 + LO2(C[1][mt]);
                floatx2 x1 = LO2(ph1[mt]) * Wf1;
                av02 += x1 * LO2(vj0[mt]);
                av12 += x1 * LO2(vj1[mt]);
                av22 += x1 * LO2(vj2[mt]);
                floatx2 Wf2 = rb2v*we2 + LO2(C[2][mt]);
                floatx2 x2 = LO2(ph2[mt]) * Wf2;
                av02 += x2 * LO2(d0);
                av12 += x2 * LO2(d1);
                av22 += x2 * LO2(d2);
            }
            // packed pair 1 (r = 2,3)
            {
                floatx2 we2 = HI2(we4);
                floatx2 Wf0 = rb0v*we2 + HI2(C[0][mt]);
                accS2 += HI2(ph0[mt]) * Wf0;
                floatx2 Wf1 = rb1v*we2 + HI2(C[1][mt]);
                floatx2 x1 = HI2(ph1[mt]) * Wf1;
                av02 += x1 * HI2(vj0[mt]);
                av12 += x1 * HI2(vj1[mt]);
                av22 += x1 * HI2(vj2[mt]);
                floatx2 Wf2 = rb2v*we2 + HI2(C[2][mt]);
                floatx2 x2 = HI2(ph2[mt]) * Wf2;
                av02 += x2 * HI2(d0);
                av12 += x2 * HI2(d1);
                av22 += x2 * HI2(d2);
            }
        }
        float accS = accS2.x + accS2.y;
        float av0 = av02.x + av02.y;
        float av1 = av12.x + av12.y;
        float av2 = av22.x + av22.y;
        accS += __shfl_xor(accS, 16, 64); accS += __shfl_xor(accS, 32, 64);
        av0 += __shfl_xor(av0, 16, 64);   av0 += __shfl_xor(av0, 32, 64);
        av1 += __shfl_xor(av1, 16, 64);   av1 += __shfl_xor(av1, 32, 64);
        av2 += __shfl_xor(av2, 16, 64);   av2 += __shfl_xor(av2, 32, 64);
        if (quad == 0) {
            sOut[(size_t)i*NF + f]        = sIn[(size_t)i*NF + f]        + accS;
            vOut[(size_t)i*F3 + f]        = vIn[(size_t)i*F3 + f]        + av0;
            vOut[(size_t)i*F3 + NF + f]   = vIn[(size_t)i*F3 + NF + f]   + av1;
            vOut[(size_t)i*F3 + 2*NF + f] = vIn[(size_t)i*F3 + 2*NF + f] + av2;
        }
    }
}

// ---------------- update (+ fused phi): 8 nodes/block, 512 thr, hi-only GEMMs ----------------
__global__ void __launch_bounds__(512) update_phi_kernel(
        const short* __restrict__ UT_h, const short* __restrict__ VT_h,
        const short* __restrict__ u1T_h, const float* __restrict__ b1,
        const short* __restrict__ u2T_h, const float* __restrict__ b2,
        float* __restrict__ s, float* __restrict__ v, float* __restrict__ vT,
        int doPhi,
        const short* __restrict__ pw1_h, const float* __restrict__ pb1,
        const short* __restrict__ pw2_h, const float* __restrict__ pb2,
        float* __restrict__ phiT) {
    __shared__ short A1h[48*NF], A1l[48*NF];   // v (hi for MFMA, hi+lo for epilogue reconstruct)
    __shared__ short A2h[16*256];              // [s ; Vn] hi; reused for s_new (phi A)
    __shared__ short hH[16*NF];
    __shared__ float sF[8*132];
    int t = threadIdx.x;
    int w = t >> 6, lane = t & 63, quad = lane >> 4, col = lane & 15;
    int raw = blockIdx.x;
    int xcd = raw & 7, idx = raw >> 3;
    int graph = xcd + 8*(idx % 12);
    int n0 = graph*NA + (idx / 12)*8;
    int f = w*16 + col;
    for (int e = t; e < 8*F3; e += 512) {
        int n = e / F3, cf = e % F3;
        int c = cf >> 7, ff = cf & 127;
        float x = v[(size_t)(n0+n)*F3 + cf];
        int row = c*16 + n;
        short h = f2bf(x);
        int ad = row*NF + (((ff >> 3) ^ (row & 7)) << 3) + (ff & 7);
        A1h[ad] = h; A1l[ad] = f2bf(x - bf2f(h));
    }
    for (int e = t; e < 8*NF; e += 512) {
        int n = e >> 7, ff = e & 127;
        float x = s[(size_t)(n0+n)*NF + ff];
        sF[n*132 + ff] = x;
        int ad = n*256 + (((ff >> 3) ^ (n & 7)) << 3) + (ff & 7);
        A2h[ad] = f2bf(x);
    }
    __syncthreads();
    floatx4 Uacc[3], Vacc[3];
    #pragma unroll
    for (int mt = 0; mt < 3; ++mt) { Uacc[mt] = (floatx4){0.f,0.f,0.f,0.f}; Vacc[mt] = (floatx4){0.f,0.f,0.f,0.f}; }
    #pragma unroll
    for (int ks = 0; ks < 4; ++ks) {
        size_t off = (size_t)(((w*4 + ks)*4 + quad)*128) + col*8;
        short8 BU = *(const short8*)(UT_h + off);
        short8 BV = *(const short8*)(VT_h + off);
        #pragma unroll
        for (int mt = 0; mt < 3; ++mt) {
            int row = mt*16 + col;
            int ad = row*NF + (((ks*4 + quad) ^ (row & 7)) << 3);
            short8 ah = *(short8*)&A1h[ad];
            Uacc[mt] = mfma1(ah, BU, Uacc[mt]);
            Vacc[mt] = mfma1(ah, BV, Vacc[mt]);
        }
    }
    if (quad < 2) {
        #pragma unroll
        for (int r = 0; r < 4; ++r) {
            int n = quad*4 + r;          // n < 8
            float v0 = Vacc[0][r], v1 = Vacc[1][r], v2 = Vacc[2][r];
            float vn = sqrtf(v0*v0 + v1*v1 + v2*v2 + 1e-8f);
            int ad = n*256 + ((((128 + f) >> 3) ^ (n & 7)) << 3) + (f & 7);
            A2h[ad] = f2bf(vn);
        }
    }
    __syncthreads();
    {
        floatx4 H = (floatx4){0.f,0.f,0.f,0.f};
        #pragma unroll
        for (int ks = 0; ks < 8; ++ks) {
            int ad = col*256 + (((ks*4 + quad) ^ (col & 7)) << 3);
            short8 ah = *(short8*)&A2h[ad];
            size_t off = (size_t)(((w*8 + ks)*4 + quad)*128) + col*8;
            H = mfma1(ah, *(const short8*)(u1T_h + off), H);
        }
        float bias = b1[f];
        if (quad < 2) {
            #pragma unroll
            for (int r = 0; r < 4; ++r) {
                int n = quad*4 + r;
                float hv = silu_f(H[r] + bias);
                int ad = n*NF + (((f >> 3) ^ (n & 7)) << 3) + (f & 7);
                hH[ad] = f2bf(hv);
            }
        }
    }
    __syncthreads();
    floatx4 O[3];
    #pragma unroll
    for (int gg = 0; gg < 3; ++gg) O[gg] = (floatx4){0.f,0.f,0.f,0.f};
    #pragma unroll
    for (int ks = 0; ks < 4; ++ks) {
        int ad = col*NF + (((ks*4 + quad) ^ (col & 7)) << 3);
        short8 ah = *(short8*)&hH[ad];
        #pragma unroll
        for (int gg = 0; gg < 3; ++gg) {
            size_t off = (size_t)((((gg*8 + w)*4 + ks)*4 + quad)*128) + col*8;
            O[gg] = mfma1(ah, *(const short8*)(u2T_h + off), O[gg]);
        }
    }
    __syncthreads();        // A2h free -> reuse for s_new (phi A operand)
    short* pH = A2h;
    if (quad < 2) {
        float bavv = b2[f], basv = b2[NF + f], bass = b2[2*NF + f];
        #pragma unroll
        for (int r = 0; r < 4; ++r) {
            int n = quad*4 + r;          // n < 8
            float avv = O[0][r] + bavv;
            float asv = O[1][r] + basv;
            float ass = O[2][r] + bass;
            float dot = Uacc[0][r]*Vacc[0][r] + Uacc[1][r]*Vacc[1][r] + Uacc[2][r]*Vacc[2][r];
            float snew = sF[n*132 + f] + asv*dot + ass;
            s[(size_t)(n0+n)*NF + f] = snew;
            int adS = n*NF + (((f >> 3) ^ (n & 7)) << 3) + (f & 7);
            pH[adS] = f2bf(snew);
            #pragma unroll
            for (int c = 0; c < 3; ++c) {
                int row = c*16 + n;
                int ad = row*NF + (((f >> 3) ^ (row & 7)) << 3) + (f & 7);
                float vold = bf2f(A1h[ad]) + bf2f(A1l[ad]);   // exact fp32 v_old
                float vnew = vold + avv*Uacc[c][r];
                v[(size_t)(n0+n)*F3 + c*NF + f] = vnew;
                vT[(size_t)(c*NF + f)*NN + n0 + n] = vnew;
            }
        }
    }
    if (!doPhi) return;
    __syncthreads();
    // phi GEMM1: wave w -> feature tile w (fh = w*16+col)
    {
        floatx4 acc = (floatx4){0.f,0.f,0.f,0.f};
        #pragma unroll
        for (int ks = 0; ks < 4; ++ks) {
            int ad = col*NF + (((ks*4 + quad) ^ (col & 7)) << 3);
            size_t off = (size_t)(((w*4 + ks)*4 + quad)*128) + col*8;
            acc = mfma1(*(short8*)&pH[ad], *(const short8*)(pw1_h + off), acc);
        }
        float bias = pb1[f];
        if (quad < 2) {
            #pragma unroll
            for (int r = 0; r < 4; ++r) {
                int n = quad*4 + r;
                float hv = silu_f(acc[r] + bias);
                int ad = n*NF + (((f >> 3) ^ (n & 7)) << 3) + (f & 7);
                hH[ad] = f2bf(hv);
            }
        }
    }
    __syncthreads();
    // phi GEMM2: 8 waves x 3 tiles (tt = (w*3+nt)*16 + col)
    #pragma unroll
    for (int nt = 0; nt < 3; ++nt) {
        int tt = (w*3 + nt)*16 + col;
        floatx4 acc = (floatx4){0.f,0.f,0.f,0.f};
        #pragma unroll
        for (int ks = 0; ks < 4; ++ks) {
            int ad = col*NF + (((ks*4 + quad) ^ (col & 7)) << 3);
            size_t off = (size_t)((((w*3 + nt)*4 + ks)*4 + quad)*128) + col*8;
            acc = mfma1(*(short8*)&hH[ad], *(const short8*)(pw2_h + off), acc);
        }
        float bias = pb2[tt];
        if (quad < 2) {
            floatx4 o;
            #pragma unroll
            for (int r = 0; r < 4; ++r) o[r] = acc[r] + bias;
            *(floatx4*)(phiT + (size_t)tt*NN + n0 + quad*4) = o;
        }
    }
}

// ---------------- output head ----------------
__global__ void zero_out_kernel(float* __restrict__ out) {
    out[threadIdx.x] = 0.f;
}

__global__ void out_kernel(const float* __restrict__ s,
                           const float* __restrict__ w1, const float* __restrict__ b1,
                           const float* __restrict__ w2, const float* __restrict__ b2,
                           float* __restrict__ out) {
    int n = blockIdx.x;
    int f = threadIdx.x;
    __shared__ float sh[NF];
    __shared__ float r2[2];
    sh[f] = s[n*NF + f];
    __syncthreads();
    float acc = b1[f];
    for (int g = 0; g < NF; ++g) acc = fmaf(sh[g], w1[g*NF + f], acc);
    float p = silu_f(acc) * w2[f];
    #pragma unroll
    for (int off = 32; off > 0; off >>= 1) p += __shfl_down(p, off, 64);
    if ((f & 63) == 0) r2[f >> 6] = p;
    __syncthreads();
    if (f == 0) atomicAdd(&out[n / NA], r2[0] + r2[1] + b2[0]);
}

extern "C" void kernel_launch(void* const* d_in, const int* in_sizes, int n_in,
                              void* d_out, int out_size, void* d_ws, size_t ws_size,
                              hipStream_t stream) {
    (void)in_sizes; (void)n_in; (void)out_size; (void)ws_size;
    const float* pos      = (const float*)d_in[1];
    const int*   node_atom= (const int*)  d_in[3];
    const float* emb      = (const float*)d_in[4];
    const float* msg_w1   = (const float*)d_in[5];
    const float* msg_b1   = (const float*)d_in[6];
    const float* msg_w2   = (const float*)d_in[7];
    const float* msg_b2   = (const float*)d_in[8];
    const float* rbf_w    = (const float*)d_in[9];
    const float* rbf_b    = (const float*)d_in[10];
    const float* upd_U    = (const float*)d_in[11];
    const float* upd_V    = (const float*)d_in[12];
    const float* upd_w1   = (const float*)d_in[13];
    const float* upd_b1   = (const float*)d_in[14];
    const float* upd_w2   = (const float*)d_in[15];
    const float* upd_b2   = (const float*)d_in[16];
    const float* out_w1   = (const float*)d_in[17];
    const float* out_b1   = (const float*)d_in[18];
    const float* out_w2   = (const float*)d_in[19];
    const float* out_b2   = (const float*)d_in[20];
    float* out = (float*)d_out;

    float* ws   = (float*)d_ws;
    float* sA   = ws; ws += (size_t)NN*NF;
    float* sB   = ws; ws += (size_t)NN*NF;
    float* vA   = ws; ws += (size_t)NN*F3;
    float* vB   = ws; ws += (size_t)NN*F3;
    float* phiT = ws; ws += (size_t)F3*NN;
    float* vT   = ws; ws += (size_t)F3*NN;
    float* dG   = ws; ws += (size_t)NN*NA;
    float* weG  = ws; ws += (size_t)NN*NA;
    float* dirG = ws; ws += (size_t)3*NN*NA;
    short* sp    = (short*)ws;
    short* w1T_h = sp; sp += (size_t)NL*NF*NF;
    short* w1T_l = sp; sp += (size_t)NL*NF*NF;
    short* w2T_h = sp; sp += (size_t)NL*F3*NF;
    short* w2T_l = sp; sp += (size_t)NL*F3*NF;
    short* rbfT_h= sp; sp += (size_t)NL*F3*NK;
    short* rbfT_l= sp; sp += (size_t)NL*F3*NK;
    short* UT_h  = sp; sp += (size_t)NL*NF*NF;
    short* UT_l  = sp; sp += (size_t)NL*NF*NF;
    short* VT_h  = sp; sp += (size_t)NL*NF*NF;
    short* VT_l  = sp; sp += (size_t)NL*NF*NF;
    short* u1T_h = sp; sp += (size_t)NL*NF*2*NF;
    short* u1T_l = sp; sp += (size_t)NL*NF*2*NF;
    short* u2T_h = sp; sp += (size_t)NL*F3*NF;
    short* u2T_l = sp; sp += (size_t)NL*F3*NF;

    prep_kernel<<<dim3(NL*384, 7), 64, 0, stream>>>(msg_w1, msg_w2, rbf_w, upd_U, upd_V, upd_w1, upd_w2,
                                                    w1T_h, w1T_l, w2T_h, w2T_l, rbfT_h, rbfT_l,
                                                    UT_h, UT_l, VT_h, VT_l, u1T_h, u1T_l, u2T_h, u2T_l);
    geom_kernel<<<(NN*NA)/256, 256, 0, stream>>>(pos, dG, weG, dirG);
    zero_kernel<<<(F3*NN)/256, 256, 0, stream>>>(vT);
    init_phi_kernel<<<NN/16, 128, 0, stream>>>(emb, node_atom,
                                               w1T_h, w1T_l, msg_b1, w2T_h, w2T_l, msg_b2,
                                               sA, vA, phiT);

    float* sC = sA; float* vC = vA; float* sN = sB; float* vN = vB;
    for (int l = 0; l < NL; ++l) {
        message_kernel<<<NB*6, 512, 0, stream>>>(sC, vC, phiT, vT,
                                                 dG, weG, dirG,
                                                 rbfT_h + (size_t)l*F3*NK,
                                                 rbf_b + (size_t)l*F3, sN, vN);
        int lp = (l + 1 < NL) ? (l + 1) : 0;
        update_phi_kernel<<<NN/8, 512, 0, stream>>>(
            UT_h + (size_t)l*NF*NF, VT_h + (size_t)l*NF*NF,
            u1T_h + (size_t)l*NF*2*NF, upd_b1 + (size_t)l*NF,
            u2T_h + (size_t)l*F3*NF, upd_b2 + (size_t)l*F3,
            sN, vN, vT,
            (l + 1 < NL) ? 1 : 0,
            w1T_h + (size_t)lp*NF*NF, msg_b1 + (size_t)lp*NF,
            w2T_h + (size_t)lp*F3*NF, msg_b2 + (size_t)lp*F3,
            phiT);
        float* tp;
        tp = sC; sC = sN; sN = tp;
        tp = vC; vC = vN; vN = tp;
    }
    zero_out_kernel<<<1, NB, 0, stream>>>(out);
    out_kernel<<<NN, NF, 0, stream>>>(sC, out_w1, out_b1, out_w2, out_b2, out);
}